// Round 5
// baseline (1019.984 us; speedup 1.0000x reference)
//
#include <hip/hip_runtime.h>

#define NU 50000
#define NI 70000
#define NT 120000
#define DD 128
#define EDG 800000
#define NCH ((NT + 255) / 256)      // 469 scan chunks
#define NBU_TN ((NU + 255) / 256)   // 196
#define NBI_TN ((NI + 255) / 256)   // 274
#define NBU_M ((NU + 63) / 64)      // 782
#define NBI_M ((NI + 63) / 64)      // 1094
#define SLOPE 0.5f

typedef __attribute__((ext_vector_type(8))) short bf16x8;
typedef __attribute__((ext_vector_type(4))) float f32x4;
typedef unsigned short u16;
typedef unsigned int u32;

__device__ __forceinline__ float lrelu(float x) { return x >= 0.f ? x : SLOPE * x; }

__device__ __forceinline__ u16 f2bf(float x) {
  union { float f; u32 u; } t; t.f = x;
  u32 r = (t.u + 0x7fffu + ((t.u >> 16) & 1u)) >> 16;
  return (u16)r;
}
__device__ __forceinline__ float bflo(u32 u) {
  union { u32 u; float f; } t; t.u = u << 16; return t.f;
}
__device__ __forceinline__ float bfhi(u32 u) {
  union { u32 u; float f; } t; t.u = u & 0xffff0000u; return t.f;
}

// ---------------- edge sort (counting sort by row) ----------------

__global__ __launch_bounds__(256)
void hist_k(const int* __restrict__ rows, int* __restrict__ cnt, int E) {
  int e = blockIdx.x * 256 + threadIdx.x;
  if (e < E) atomicAdd(&cnt[rows[e]], 1);
}

__global__ __launch_bounds__(256)
void scan1_k(const int* __restrict__ cnt, int* __restrict__ tmp, int* __restrict__ part) {
  __shared__ int s[256];
  int gid = blockIdx.x * 256 + threadIdx.x;
  s[threadIdx.x] = (gid < NT) ? cnt[gid] : 0;
  __syncthreads();
#pragma unroll
  for (int off = 1; off < 256; off <<= 1) {
    int add = (threadIdx.x >= off) ? s[threadIdx.x - off] : 0;
    __syncthreads();
    s[threadIdx.x] += add;
    __syncthreads();
  }
  if (gid < NT) tmp[gid] = s[threadIdx.x];
  if (threadIdx.x == 255) part[blockIdx.x] = s[255];
}

__global__ __launch_bounds__(512)
void scan2_k(int* __restrict__ part) {
  __shared__ int s[512];
  s[threadIdx.x] = (threadIdx.x < NCH) ? part[threadIdx.x] : 0;
  __syncthreads();
#pragma unroll
  for (int off = 1; off < 512; off <<= 1) {
    int add = (threadIdx.x >= off) ? s[threadIdx.x - off] : 0;
    __syncthreads();
    s[threadIdx.x] += add;
    __syncthreads();
  }
  if (threadIdx.x < NCH) part[threadIdx.x] = s[threadIdx.x];
}

__global__ __launch_bounds__(256)
void scan3_k(const int* __restrict__ tmp, const int* __restrict__ part,
             int* __restrict__ row_ptr) {
  int gid = blockIdx.x * 256 + threadIdx.x;
  if (gid < NT) {
    int off = blockIdx.x ? part[blockIdx.x - 1] : 0;
    row_ptr[gid + 1] = tmp[gid] + off;
  }
  if (gid == 0) row_ptr[0] = 0;
}

__global__ __launch_bounds__(256)
void scatter_k(const int* __restrict__ rows, const int* __restrict__ cols,
               const float* __restrict__ vals, const int* __restrict__ row_ptr,
               int* __restrict__ cursor, int2* __restrict__ sedge, int E) {
  int e = blockIdx.x * 256 + threadIdx.x;
  if (e >= E) return;
  int r = rows[e];
  int p = row_ptr[r] + atomicAdd(&cursor[r], 1);
  int2 ev; ev.x = cols[e]; ev.y = __float_as_int(vals[e]);
  sedge[p] = ev;
}

// out[r,:] = lrelu(sum_e val * src[col,:]) ; bf16 source, 1 wave/row, 2 dims/lane.
__global__ __launch_bounds__(256)
void spmm_row_k(const int* __restrict__ rp, const int2* __restrict__ se,
                const u16* __restrict__ pb, float* __restrict__ G) {
  int wv = threadIdx.x >> 6, lane = threadIdx.x & 63;
  int r = blockIdx.x * 4 + wv;
  int p0 = rp[r], p1 = rp[r + 1];
  float ax = 0.f, ay = 0.f;
  int p = p0;
  for (; p + 2 <= p1; p += 2) {
    int2 ea = se[p];
    int2 eb = se[p + 1];
    u32 ua = *(const u32*)(pb + (size_t)ea.x * DD + lane * 2);
    u32 ub = *(const u32*)(pb + (size_t)eb.x * DD + lane * 2);
    float va = __int_as_float(ea.y), vb = __int_as_float(eb.y);
    ax = fmaf(va, bflo(ua), ax); ay = fmaf(va, bfhi(ua), ay);
    ax = fmaf(vb, bflo(ub), ax); ay = fmaf(vb, bfhi(ub), ay);
  }
  if (p < p1) {
    int2 e = se[p];
    u32 u = *(const u32*)(pb + (size_t)e.x * DD + lane * 2);
    float v = __int_as_float(e.y);
    ax = fmaf(v, bflo(u), ax); ay = fmaf(v, bfhi(u), ay);
  }
  float2 o; o.x = lrelu(ax); o.y = lrelu(ay);
  *(float2*)(G + (size_t)r * DD + lane * 2) = o;
}

// ---------------- dense kernels ----------------

// block 0: uhT = bf16(u_hyp^T); block 1: ihT = bf16(i_hyp^T)
__global__ __launch_bounds__(256)
void transp_both(const float* __restrict__ uh, const float* __restrict__ ih,
                 u16* __restrict__ uhT, u16* __restrict__ ihT) {
  const float* B = blockIdx.x ? ih : uh;
  u16* BT = blockIdx.x ? ihT : uhT;
  for (int i = threadIdx.x; i < 16384; i += 256) {
    int r = i >> 7, c = i & 127;
    BT[c * 128 + r] = f2bf(B[r * 128 + c]);
  }
}

// projections: uuHb = bf16(emb @ hyp) for users+items; also emits e0bf = bf16(embeds0).
__global__ __launch_bounds__(256)
void proj_mfma(const float* __restrict__ Au, const float* __restrict__ Ai,
               const u16* __restrict__ BTu, const u16* __restrict__ BTi,
               u16* __restrict__ uuHb, u16* __restrict__ e0bf) {
  int b = blockIdx.x;
  bool usr = b < NBU_M;
  const float* A = usr ? Au : Ai;
  const u16* BT = usr ? BTu : BTi;
  int n = usr ? NU : NI;
  int lb = usr ? b : b - NBU_M;
  int gbase = usr ? 0 : NU;

  int wv = threadIdx.x >> 6, lane = threadIdx.x & 63;
  int t = lane & 15, g = lane >> 4;
  int rowa = lb * 64 + wv * 16 + t;
  int ra = rowa < n ? rowa : (n - 1);
  const float* ap = A + (size_t)ra * DD;

  bf16x8 af[4];
#pragma unroll
  for (int k0 = 0; k0 < 4; ++k0) {
    float4 x = *(const float4*)(ap + k0 * 32 + g * 8);
    float4 y = *(const float4*)(ap + k0 * 32 + g * 8 + 4);
    bf16x8 v;
    v[0] = (short)f2bf(x.x); v[1] = (short)f2bf(x.y);
    v[2] = (short)f2bf(x.z); v[3] = (short)f2bf(x.w);
    v[4] = (short)f2bf(y.x); v[5] = (short)f2bf(y.y);
    v[6] = (short)f2bf(y.z); v[7] = (short)f2bf(y.w);
    af[k0] = v;
  }

  // free bf16 copy of embeds0 (row already converted in registers)
  if (rowa < n) {
#pragma unroll
    for (int k0 = 0; k0 < 4; ++k0)
      *(bf16x8*)(e0bf + (size_t)(gbase + rowa) * DD + k0 * 32 + g * 8) = af[k0];
  }

  f32x4 acc[8];
#pragma unroll
  for (int cb = 0; cb < 8; ++cb) acc[cb] = (f32x4){0.f, 0.f, 0.f, 0.f};
#pragma unroll
  for (int k0 = 0; k0 < 4; ++k0)
#pragma unroll
    for (int cb = 0; cb < 8; ++cb) {
      bf16x8 bfr = *(const bf16x8*)(BT + (size_t)(cb * 16 + t) * 128 + k0 * 32 + g * 8);
      acc[cb] = __builtin_amdgcn_mfma_f32_16x16x32_bf16(af[k0], bfr, acc[cb], 0, 0, 0);
    }

  int rbase = lb * 64 + wv * 16 + g * 4;
#pragma unroll
  for (int cb = 0; cb < 8; ++cb)
#pragma unroll
    for (int j = 0; j < 4; ++j) {
      int lr = rbase + j;
      if (lr < n) uuHb[(size_t)(gbase + lr) * DD + cb * 16 + t] = f2bf(acc[cb][j]);
    }
}

// hyper GEMM (A = bf16 uuHb) + fused epilogue.
// LAYER 0: H=lrelu(acc), prev=G+H (fp32+bf16). LAYER 1: out=e0+prev+G+H.
template<int LAYER>
__global__ __launch_bounds__(256)
void hyp_mfma(const u16* __restrict__ Ab,
              const u16* __restrict__ BTu, const u16* __restrict__ BTi,
              const float* __restrict__ G, float* __restrict__ prev,
              u16* __restrict__ prevb,
              const float* __restrict__ ue, const float* __restrict__ ie,
              float* __restrict__ H, float* __restrict__ out) {
  int b = blockIdx.x;
  bool usr = b < NBU_M;
  const u16* BT = usr ? BTu : BTi;
  int n = usr ? NU : NI;
  int lb = usr ? b : b - NBU_M;
  int gbase = usr ? 0 : NU;

  int wv = threadIdx.x >> 6, lane = threadIdx.x & 63;
  int t = lane & 15, g = lane >> 4;
  int rowa = lb * 64 + wv * 16 + t;
  int ra = rowa < n ? rowa : (n - 1);
  const u16* ap = Ab + (size_t)(gbase + ra) * DD;

  bf16x8 af[4];
#pragma unroll
  for (int k0 = 0; k0 < 4; ++k0)
    af[k0] = *(const bf16x8*)(ap + k0 * 32 + g * 8);

  f32x4 acc[8];
#pragma unroll
  for (int cb = 0; cb < 8; ++cb) acc[cb] = (f32x4){0.f, 0.f, 0.f, 0.f};
#pragma unroll
  for (int k0 = 0; k0 < 4; ++k0)
#pragma unroll
    for (int cb = 0; cb < 8; ++cb) {
      bf16x8 bfr = *(const bf16x8*)(BT + (size_t)(cb * 16 + t) * 128 + k0 * 32 + g * 8);
      acc[cb] = __builtin_amdgcn_mfma_f32_16x16x32_bf16(af[k0], bfr, acc[cb], 0, 0, 0);
    }

  int rbase = lb * 64 + wv * 16 + g * 4;
#pragma unroll
  for (int cb = 0; cb < 8; ++cb)
#pragma unroll
    for (int j = 0; j < 4; ++j) {
      int lr = rbase + j;
      if (lr < n) {
        size_t gi = (size_t)(gbase + lr) * DD + cb * 16 + t;
        float h = lrelu(acc[cb][j]);
        H[gi] = h;
        if (LAYER == 0) {
          float pv = G[gi] + h;
          prev[gi] = pv;
          prevb[gi] = f2bf(pv);
        } else {
          float e0 = usr ? ue[(size_t)lr * DD + cb * 16 + t]
                         : ie[(size_t)lr * DD + cb * 16 + t];
          out[gi] = e0 + prev[gi] + G[gi] + h;
        }
      }
    }
}

// lat reductions: latU += uuHb^T @ Bb (users rows), latI += (items rows).
// bf16 global direct loads, no LDS, no syncthreads.
__global__ __launch_bounds__(256)
void tn_both(const u16* __restrict__ Ab, const u16* __restrict__ Bb,
             float* __restrict__ latU, float* __restrict__ latI) {
  int b = blockIdx.x;
  bool usr = b < NBU_TN;
  int n = usr ? NU : NI;
  int gbase = usr ? 0 : NU;
  float* outp = usr ? latU : latI;
  int r0 = (usr ? b : b - NBU_TN) * 256;
  int r1 = min(r0 + 256, n);

  int ty = threadIdx.x >> 4, tx = threadIdx.x & 15;
  float acc[8][8];
#pragma unroll
  for (int i = 0; i < 8; ++i)
#pragma unroll
    for (int j = 0; j < 8; ++j) acc[i][j] = 0.f;

  for (int rb = r0; rb < r1; rb += 8) {   // (r1-r0) always divisible by 8
#pragma unroll
    for (int r2 = 0; r2 < 8; ++r2) {
      size_t ro = (size_t)(gbase + rb + r2) * DD;
      uint4 au = *(const uint4*)(Ab + ro + ty * 8);
      uint2 b0 = *(const uint2*)(Bb + ro + tx * 4);
      uint2 b1 = *(const uint2*)(Bb + ro + tx * 4 + 64);
      float a[8] = {bflo(au.x), bfhi(au.x), bflo(au.y), bfhi(au.y),
                    bflo(au.z), bfhi(au.z), bflo(au.w), bfhi(au.w)};
      float bb[8] = {bflo(b0.x), bfhi(b0.x), bflo(b0.y), bfhi(b0.y),
                     bflo(b1.x), bfhi(b1.x), bflo(b1.y), bfhi(b1.y)};
#pragma unroll
      for (int i = 0; i < 8; ++i)
#pragma unroll
        for (int j = 0; j < 8; ++j)
          acc[i][j] = fmaf(a[i], bb[j], acc[i][j]);
    }
  }

#pragma unroll
  for (int i = 0; i < 8; ++i) {
    int h = ty * 8 + i;
#pragma unroll
    for (int j = 0; j < 8; ++j) {
      int d = tx * 4 + (j < 4 ? j : 64 + (j - 4));
      atomicAdd(outp + h * DD + d, acc[i][j]);
    }
  }
}

// pass 1: out = lrelu(V @ L) + L, where L = lrelu(in_raw). merged u/i, 32 blocks.
__global__ __launch_bounds__(256)
void vg1_k(const float* __restrict__ V, const float* __restrict__ inU,
           const float* __restrict__ inI, float* __restrict__ outU,
           float* __restrict__ outI) {
  const float* in = blockIdx.x < 16 ? inU : inI;
  float* outp = blockIdx.x < 16 ? outU : outI;
  int row = (blockIdx.x & 15) * 8 + (threadIdx.x >> 5);
  int c4 = (threadIdx.x & 31) * 4;
  float4 acc = make_float4(0.f, 0.f, 0.f, 0.f);
  for (int k = 0; k < 128; ++k) {
    float v = V[row * 128 + k];
    float4 l = *(const float4*)(in + k * 128 + c4);
    l.x = lrelu(l.x); l.y = lrelu(l.y); l.z = lrelu(l.z); l.w = lrelu(l.w);
    acc.x = fmaf(v, l.x, acc.x);
    acc.y = fmaf(v, l.y, acc.y);
    acc.z = fmaf(v, l.z, acc.z);
    acc.w = fmaf(v, l.w, acc.w);
  }
  float4 r = *(const float4*)(in + row * 128 + c4);
  float4 o;
  o.x = lrelu(acc.x) + lrelu(r.x);
  o.y = lrelu(acc.y) + lrelu(r.y);
  o.z = lrelu(acc.z) + lrelu(r.z);
  o.w = lrelu(acc.w) + lrelu(r.w);
  *(float4*)(outp + row * 128 + c4) = o;
}

// pass 2: BT = bf16( (lrelu(V @ L) + L)^T ). merged u/i.
__global__ __launch_bounds__(256)
void vg2_k(const float* __restrict__ V, const float* __restrict__ inU,
           const float* __restrict__ inI, u16* __restrict__ outU,
           u16* __restrict__ outI) {
  const float* in = blockIdx.x < 16 ? inU : inI;
  u16* BT = blockIdx.x < 16 ? outU : outI;
  int row = (blockIdx.x & 15) * 8 + (threadIdx.x >> 5);
  int c4 = (threadIdx.x & 31) * 4;
  float4 acc = make_float4(0.f, 0.f, 0.f, 0.f);
  for (int k = 0; k < 128; ++k) {
    float v = V[row * 128 + k];
    float4 l = *(const float4*)(in + k * 128 + c4);
    acc.x = fmaf(v, l.x, acc.x);
    acc.y = fmaf(v, l.y, acc.y);
    acc.z = fmaf(v, l.z, acc.z);
    acc.w = fmaf(v, l.w, acc.w);
  }
  float4 r = *(const float4*)(in + row * 128 + c4);
  BT[(size_t)(c4 + 0) * 128 + row] = f2bf(lrelu(acc.x) + r.x);
  BT[(size_t)(c4 + 1) * 128 + row] = f2bf(lrelu(acc.y) + r.y);
  BT[(size_t)(c4 + 2) * 128 + row] = f2bf(lrelu(acc.z) + r.z);
  BT[(size_t)(c4 + 3) * 128 + row] = f2bf(lrelu(acc.w) + r.w);
}

extern "C" void kernel_launch(void* const* d_in, const int* in_sizes, int n_in,
                              void* d_out, int out_size, void* d_ws, size_t ws_size,
                              hipStream_t stream) {
  const float* u_emb = (const float*)d_in[0];
  const float* i_emb = (const float*)d_in[1];
  const float* u_hyp = (const float*)d_in[2];
  const float* i_hyp = (const float*)d_in[3];
  const float* Vm    = (const float*)d_in[4];
  const int*   rows  = (const int*)d_in[5];
  const int*   cols  = (const int*)d_in[6];
  const float* vals  = (const float*)d_in[7];
  int E = in_sizes[5];

  float* out = (float*)d_out;
  float* OUT_G = out + (size_t)NT * DD;        // gnn_lats [2,N,D]
  float* OUT_H = out + (size_t)3 * NT * DD;    // hyper_lats [2,N,D]

  char* w = (char*)d_ws;
  float* prev = (float*)w;            w += (size_t)NT * DD * 4;
  u16* uuHb   = (u16*)w;              w += (size_t)NT * DD * 2;
  u16* e0bf   = (u16*)w;              w += (size_t)NT * DD * 2;
  u16* prevb  = (u16*)w;              w += (size_t)NT * DD * 2;
  float* latU = (float*)w;            w += 16384 * 4;
  float* latI = (float*)w;            w += 16384 * 4;   // contiguous with latU
  float* lat2U = (float*)w;           w += 16384 * 4;
  float* lat2I = (float*)w;           w += 16384 * 4;
  u16* uhT    = (u16*)w;              w += 16384 * 2;
  u16* ihT    = (u16*)w;              w += 16384 * 2;
  u16* latTu  = (u16*)w;              w += 16384 * 2;
  u16* latTi  = (u16*)w;              w += 16384 * 2;
  int* row_cnt = (int*)w;             w += (size_t)NT * 4;
  int* cursor  = (int*)w;             w += (size_t)NT * 4;  // contiguous with row_cnt
  int* row_ptr = (int*)w;             w += (size_t)(NT + 1) * 4;
  int* tmp     = (int*)w;             w += (size_t)NT * 4;
  int* part    = (int*)w;             w += 512 * 4;
  int2* sedge  = (int2*)w;            w += (size_t)EDG * 8;

  // ---- sort edges by row (once; reused by both layers) ----
  hipMemsetAsync(row_cnt, 0, sizeof(int) * 2 * NT, stream);   // row_cnt + cursor
  hist_k<<<(E + 255) / 256, 256, 0, stream>>>(rows, row_cnt, E);
  scan1_k<<<NCH, 256, 0, stream>>>(row_cnt, tmp, part);
  scan2_k<<<1, 512, 0, stream>>>(part);
  scan3_k<<<NCH, 256, 0, stream>>>(tmp, part, row_ptr);
  scatter_k<<<(E + 255) / 256, 256, 0, stream>>>(rows, cols, vals, row_ptr,
                                                 cursor, sedge, E);

  // ---- hyper projections (also emits e0bf) ----
  transp_both<<<2, 256, 0, stream>>>(u_hyp, i_hyp, uhT, ihT);
  proj_mfma<<<NBU_M + NBI_M, 256, 0, stream>>>(u_emb, i_emb, uhT, ihT, uuHb, e0bf);

  for (int k = 0; k < 2; ++k) {
    float* G = OUT_G + (size_t)k * NT * DD;
    float* H = OUT_H + (size_t)k * NT * DD;
    const u16* pb = k == 0 ? e0bf : prevb;

    // tem = leaky(spmm(prev))
    spmm_row_k<<<NT / 4, 256, 0, stream>>>(row_ptr, sedge, pb, G);

    // hgnn lat chain (users + items merged)
    hipMemsetAsync(latU, 0, sizeof(float) * 2 * 16384, stream);
    tn_both<<<NBU_TN + NBI_TN, 256, 0, stream>>>(uuHb, pb, latU, latI);
    vg1_k<<<32, 256, 0, stream>>>(Vm, latU, latI, lat2U, lat2I);
    vg2_k<<<32, 256, 0, stream>>>(Vm, lat2U, lat2I, latTu, latTi);

    // H = lrelu(A @ lat) with fused epilogue
    if (k == 0)
      hyp_mfma<0><<<NBU_M + NBI_M, 256, 0, stream>>>(
          uuHb, latTu, latTi, G, prev, prevb, u_emb, i_emb, H, out);
    else
      hyp_mfma<1><<<NBU_M + NBI_M, 256, 0, stream>>>(
          uuHb, latTu, latTi, G, prev, prevb, u_emb, i_emb, H, out);
  }
}

// Round 6
// 649.571 us; speedup vs baseline: 1.5702x; 1.5702x over previous
//
#include <hip/hip_runtime.h>

#define NU 50000
#define NI 70000
#define NT 120000
#define DD 128
#define EDG 800000
#define NCH ((NT + 255) / 256)      // 469 scan chunks
#define NBU_TN ((NU + 255) / 256)   // 196
#define NBI_TN ((NI + 255) / 256)   // 274
#define NBU_M ((NU + 63) / 64)      // 782
#define NBI_M ((NI + 63) / 64)      // 1094
#define SLOPE 0.5f

typedef __attribute__((ext_vector_type(8))) short bf16x8;
typedef __attribute__((ext_vector_type(4))) float f32x4;
typedef unsigned short u16;
typedef unsigned int u32;

__device__ __forceinline__ float lrelu(float x) { return x >= 0.f ? x : SLOPE * x; }

__device__ __forceinline__ u16 f2bf(float x) {
  union { float f; u32 u; } t; t.f = x;
  u32 r = (t.u + 0x7fffu + ((t.u >> 16) & 1u)) >> 16;
  return (u16)r;
}
__device__ __forceinline__ float bflo(u32 u) {
  union { u32 u; float f; } t; t.u = u << 16; return t.f;
}
__device__ __forceinline__ float bfhi(u32 u) {
  union { u32 u; float f; } t; t.u = u & 0xffff0000u; return t.f;
}

// ---------------- edge sort (counting sort by row) ----------------

__global__ __launch_bounds__(256)
void hist_k(const int* __restrict__ rows, int* __restrict__ cnt, int E) {
  int e = blockIdx.x * 256 + threadIdx.x;
  if (e < E) atomicAdd(&cnt[rows[e]], 1);
}

__global__ __launch_bounds__(256)
void scan1_k(const int* __restrict__ cnt, int* __restrict__ tmp, int* __restrict__ part) {
  __shared__ int s[256];
  int gid = blockIdx.x * 256 + threadIdx.x;
  s[threadIdx.x] = (gid < NT) ? cnt[gid] : 0;
  __syncthreads();
#pragma unroll
  for (int off = 1; off < 256; off <<= 1) {
    int add = (threadIdx.x >= off) ? s[threadIdx.x - off] : 0;
    __syncthreads();
    s[threadIdx.x] += add;
    __syncthreads();
  }
  if (gid < NT) tmp[gid] = s[threadIdx.x];
  if (threadIdx.x == 255) part[blockIdx.x] = s[255];
}

__global__ __launch_bounds__(512)
void scan2_k(int* __restrict__ part) {
  __shared__ int s[512];
  s[threadIdx.x] = (threadIdx.x < NCH) ? part[threadIdx.x] : 0;
  __syncthreads();
#pragma unroll
  for (int off = 1; off < 512; off <<= 1) {
    int add = (threadIdx.x >= off) ? s[threadIdx.x - off] : 0;
    __syncthreads();
    s[threadIdx.x] += add;
    __syncthreads();
  }
  if (threadIdx.x < NCH) part[threadIdx.x] = s[threadIdx.x];
}

__global__ __launch_bounds__(256)
void scan3_k(const int* __restrict__ tmp, const int* __restrict__ part,
             int* __restrict__ row_ptr) {
  int gid = blockIdx.x * 256 + threadIdx.x;
  if (gid < NT) {
    int off = blockIdx.x ? part[blockIdx.x - 1] : 0;
    row_ptr[gid + 1] = tmp[gid] + off;
  }
  if (gid == 0) row_ptr[0] = 0;
}

__global__ __launch_bounds__(256)
void scatter_k(const int* __restrict__ rows, const int* __restrict__ cols,
               const float* __restrict__ vals, const int* __restrict__ row_ptr,
               int* __restrict__ cursor, int2* __restrict__ sedge, int E) {
  int e = blockIdx.x * 256 + threadIdx.x;
  if (e >= E) return;
  int r = rows[e];
  int p = row_ptr[r] + atomicAdd(&cursor[r], 1);
  int2 ev; ev.x = cols[e]; ev.y = __float_as_int(vals[e]);
  sedge[p] = ev;
}

// out[r,:] = lrelu(sum_e val * src[col,:]) ; bf16 source, 1 wave/row, 2 dims/lane.
__global__ __launch_bounds__(256)
void spmm_row_k(const int* __restrict__ rp, const int2* __restrict__ se,
                const u16* __restrict__ pb, float* __restrict__ G) {
  int wv = threadIdx.x >> 6, lane = threadIdx.x & 63;
  int r = blockIdx.x * 4 + wv;
  int p0 = rp[r], p1 = rp[r + 1];
  float ax = 0.f, ay = 0.f;
  int p = p0;
  for (; p + 2 <= p1; p += 2) {
    int2 ea = se[p];
    int2 eb = se[p + 1];
    u32 ua = *(const u32*)(pb + (size_t)ea.x * DD + lane * 2);
    u32 ub = *(const u32*)(pb + (size_t)eb.x * DD + lane * 2);
    float va = __int_as_float(ea.y), vb = __int_as_float(eb.y);
    ax = fmaf(va, bflo(ua), ax); ay = fmaf(va, bfhi(ua), ay);
    ax = fmaf(vb, bflo(ub), ax); ay = fmaf(vb, bfhi(ub), ay);
  }
  if (p < p1) {
    int2 e = se[p];
    u32 u = *(const u32*)(pb + (size_t)e.x * DD + lane * 2);
    float v = __int_as_float(e.y);
    ax = fmaf(v, bflo(u), ax); ay = fmaf(v, bfhi(u), ay);
  }
  float2 o; o.x = lrelu(ax); o.y = lrelu(ay);
  *(float2*)(G + (size_t)r * DD + lane * 2) = o;
}

// ---------------- dense kernels ----------------

// block 0: uhT = bf16(u_hyp^T); block 1: ihT = bf16(i_hyp^T)
__global__ __launch_bounds__(256)
void transp_both(const float* __restrict__ uh, const float* __restrict__ ih,
                 u16* __restrict__ uhT, u16* __restrict__ ihT) {
  const float* B = blockIdx.x ? ih : uh;
  u16* BT = blockIdx.x ? ihT : uhT;
  for (int i = threadIdx.x; i < 16384; i += 256) {
    int r = i >> 7, c = i & 127;
    BT[c * 128 + r] = f2bf(B[r * 128 + c]);
  }
}

// projections: uuHb = bf16(emb @ hyp) for users+items; also emits e0bf = bf16(embeds0).
__global__ __launch_bounds__(256)
void proj_mfma(const float* __restrict__ Au, const float* __restrict__ Ai,
               const u16* __restrict__ BTu, const u16* __restrict__ BTi,
               u16* __restrict__ uuHb, u16* __restrict__ e0bf) {
  int b = blockIdx.x;
  bool usr = b < NBU_M;
  const float* A = usr ? Au : Ai;
  const u16* BT = usr ? BTu : BTi;
  int n = usr ? NU : NI;
  int lb = usr ? b : b - NBU_M;
  int gbase = usr ? 0 : NU;

  int wv = threadIdx.x >> 6, lane = threadIdx.x & 63;
  int t = lane & 15, g = lane >> 4;
  int rowa = lb * 64 + wv * 16 + t;
  int ra = rowa < n ? rowa : (n - 1);
  const float* ap = A + (size_t)ra * DD;

  bf16x8 af[4];
#pragma unroll
  for (int k0 = 0; k0 < 4; ++k0) {
    float4 x = *(const float4*)(ap + k0 * 32 + g * 8);
    float4 y = *(const float4*)(ap + k0 * 32 + g * 8 + 4);
    bf16x8 v;
    v[0] = (short)f2bf(x.x); v[1] = (short)f2bf(x.y);
    v[2] = (short)f2bf(x.z); v[3] = (short)f2bf(x.w);
    v[4] = (short)f2bf(y.x); v[5] = (short)f2bf(y.y);
    v[6] = (short)f2bf(y.z); v[7] = (short)f2bf(y.w);
    af[k0] = v;
  }

  // free bf16 copy of embeds0 (row already converted in registers)
  if (rowa < n) {
#pragma unroll
    for (int k0 = 0; k0 < 4; ++k0)
      *(bf16x8*)(e0bf + (size_t)(gbase + rowa) * DD + k0 * 32 + g * 8) = af[k0];
  }

  f32x4 acc[8];
#pragma unroll
  for (int cb = 0; cb < 8; ++cb) acc[cb] = (f32x4){0.f, 0.f, 0.f, 0.f};
#pragma unroll
  for (int k0 = 0; k0 < 4; ++k0)
#pragma unroll
    for (int cb = 0; cb < 8; ++cb) {
      bf16x8 bfr = *(const bf16x8*)(BT + (size_t)(cb * 16 + t) * 128 + k0 * 32 + g * 8);
      acc[cb] = __builtin_amdgcn_mfma_f32_16x16x32_bf16(af[k0], bfr, acc[cb], 0, 0, 0);
    }

  int rbase = lb * 64 + wv * 16 + g * 4;
#pragma unroll
  for (int cb = 0; cb < 8; ++cb)
#pragma unroll
    for (int j = 0; j < 4; ++j) {
      int lr = rbase + j;
      if (lr < n) uuHb[(size_t)(gbase + lr) * DD + cb * 16 + t] = f2bf(acc[cb][j]);
    }
}

// hyper GEMM (A = bf16 uuHb) + fused epilogue.
// LAYER 0: H=lrelu(acc), prev=G+H (fp32+bf16). LAYER 1: out=e0+prev+G+H.
template<int LAYER>
__global__ __launch_bounds__(256)
void hyp_mfma(const u16* __restrict__ Ab,
              const u16* __restrict__ BTu, const u16* __restrict__ BTi,
              const float* __restrict__ G, float* __restrict__ prev,
              u16* __restrict__ prevb,
              const float* __restrict__ ue, const float* __restrict__ ie,
              float* __restrict__ H, float* __restrict__ out) {
  int b = blockIdx.x;
  bool usr = b < NBU_M;
  const u16* BT = usr ? BTu : BTi;
  int n = usr ? NU : NI;
  int lb = usr ? b : b - NBU_M;
  int gbase = usr ? 0 : NU;

  int wv = threadIdx.x >> 6, lane = threadIdx.x & 63;
  int t = lane & 15, g = lane >> 4;
  int rowa = lb * 64 + wv * 16 + t;
  int ra = rowa < n ? rowa : (n - 1);
  const u16* ap = Ab + (size_t)(gbase + ra) * DD;

  bf16x8 af[4];
#pragma unroll
  for (int k0 = 0; k0 < 4; ++k0)
    af[k0] = *(const bf16x8*)(ap + k0 * 32 + g * 8);

  f32x4 acc[8];
#pragma unroll
  for (int cb = 0; cb < 8; ++cb) acc[cb] = (f32x4){0.f, 0.f, 0.f, 0.f};
#pragma unroll
  for (int k0 = 0; k0 < 4; ++k0)
#pragma unroll
    for (int cb = 0; cb < 8; ++cb) {
      bf16x8 bfr = *(const bf16x8*)(BT + (size_t)(cb * 16 + t) * 128 + k0 * 32 + g * 8);
      acc[cb] = __builtin_amdgcn_mfma_f32_16x16x32_bf16(af[k0], bfr, acc[cb], 0, 0, 0);
    }

  int rbase = lb * 64 + wv * 16 + g * 4;
#pragma unroll
  for (int cb = 0; cb < 8; ++cb)
#pragma unroll
    for (int j = 0; j < 4; ++j) {
      int lr = rbase + j;
      if (lr < n) {
        size_t gi = (size_t)(gbase + lr) * DD + cb * 16 + t;
        float h = lrelu(acc[cb][j]);
        H[gi] = h;
        if (LAYER == 0) {
          float pv = G[gi] + h;
          prev[gi] = pv;
          prevb[gi] = f2bf(pv);
        } else {
          float e0 = usr ? ue[(size_t)lr * DD + cb * 16 + t]
                         : ie[(size_t)lr * DD + cb * 16 + t];
          out[gi] = e0 + prev[gi] + G[gi] + h;
        }
      }
    }
}

// lat reduction via MFMA: lat[h][d] += sum_r A[r][h]*B[r][d] over this block's
// row chunk. 32-row K-slabs staged in LDS transposed+pair-packed:
// AT[c][rp] (u32 = rows 2rp|2rp+1 of col c), swizzled rp^=((c&3)<<2) so
// fragment reads are contiguous 16B ds_read_b128.
__global__ __launch_bounds__(256)
void tn_mfma(const u16* __restrict__ Ab, const u16* __restrict__ Bb,
             float* __restrict__ latU, float* __restrict__ latI) {
  __shared__ u32 ATs[2048];   // [128 c][16 rp] u32
  __shared__ u32 BTs[2048];
  int b = blockIdx.x;
  bool usr = b < NBU_TN;
  int n = usr ? NU : NI;
  int gbase = usr ? 0 : NU;
  float* outp = usr ? latU : latI;
  int r0c = (usr ? b : b - NBU_TN) * 256;
  int r1c = min(r0c + 256, n);

  int tid = threadIdx.x;
  int rp = tid & 15;           // row-pair index within 32-row slab
  int sg = tid >> 4;           // 0..15 : 8-col segment
  int wv = tid >> 6, lane = tid & 63;
  int t = lane & 15, g = lane >> 4;
  int wr = wv >> 1, wc = wv & 1;   // wave tile: 4 h-tiles x 4 d-tiles

  f32x4 acc[4][4];
#pragma unroll
  for (int a = 0; a < 4; ++a)
#pragma unroll
    for (int c2 = 0; c2 < 4; ++c2) acc[a][c2] = (f32x4){0.f, 0.f, 0.f, 0.f};

  for (int r0 = r0c; r0 < r1c; r0 += 32) {
    int ra = r0 + 2 * rp, rb2 = ra + 1;
    uint4 a0 = {0,0,0,0}, a1 = {0,0,0,0}, b0 = {0,0,0,0}, b1 = {0,0,0,0};
    if (ra < r1c) {
      a0 = *(const uint4*)(Ab + (size_t)(gbase + ra) * DD + sg * 8);
      b0 = *(const uint4*)(Bb + (size_t)(gbase + ra) * DD + sg * 8);
    }
    if (rb2 < r1c) {
      a1 = *(const uint4*)(Ab + (size_t)(gbase + rb2) * DD + sg * 8);
      b1 = *(const uint4*)(Bb + (size_t)(gbase + rb2) * DD + sg * 8);
    }
    __syncthreads();   // previous slab's reads complete
#pragma unroll
    for (int j = 0; j < 8; ++j) {
      u32 alo = ((const u32*)&a0)[j >> 1], ahi = ((const u32*)&a1)[j >> 1];
      u32 blo = ((const u32*)&b0)[j >> 1], bhi = ((const u32*)&b1)[j >> 1];
      u32 wa, wb;
      if (j & 1) {
        wa = (alo >> 16) | (ahi & 0xffff0000u);
        wb = (blo >> 16) | (bhi & 0xffff0000u);
      } else {
        wa = (alo & 0xffffu) | (ahi << 16);
        wb = (blo & 0xffffu) | (bhi << 16);
      }
      int c = sg * 8 + j;
      int idx = c * 16 + (rp ^ ((j & 3) << 2));
      ATs[idx] = wa;
      BTs[idx] = wb;
    }
    __syncthreads();   // slab visible

    bf16x8 afr[4], bfr[4];
#pragma unroll
    for (int a = 0; a < 4; ++a) {
      int c = (wr * 4 + a) * 16 + t;
      afr[a] = *(const bf16x8*)&ATs[c * 16 + ((g ^ (c & 3)) << 2)];
    }
#pragma unroll
    for (int c2 = 0; c2 < 4; ++c2) {
      int c = (wc * 4 + c2) * 16 + t;
      bfr[c2] = *(const bf16x8*)&BTs[c * 16 + ((g ^ (c & 3)) << 2)];
    }
#pragma unroll
    for (int a = 0; a < 4; ++a)
#pragma unroll
      for (int c2 = 0; c2 < 4; ++c2)
        acc[a][c2] = __builtin_amdgcn_mfma_f32_16x16x32_bf16(
            afr[a], bfr[c2], acc[a][c2], 0, 0, 0);
  }

#pragma unroll
  for (int a = 0; a < 4; ++a) {
    int h = (wr * 4 + a) * 16 + g * 4;
#pragma unroll
    for (int c2 = 0; c2 < 4; ++c2) {
      int d = (wc * 4 + c2) * 16 + t;
#pragma unroll
      for (int j = 0; j < 4; ++j)
        atomicAdd(outp + (h + j) * 128 + d, acc[a][c2][j]);
    }
  }
}

// pass 1: out = lrelu(V @ L) + L, where L = lrelu(in_raw). merged u/i, 32 blocks.
__global__ __launch_bounds__(256)
void vg1_k(const float* __restrict__ V, const float* __restrict__ inU,
           const float* __restrict__ inI, float* __restrict__ outU,
           float* __restrict__ outI) {
  const float* in = blockIdx.x < 16 ? inU : inI;
  float* outp = blockIdx.x < 16 ? outU : outI;
  int row = (blockIdx.x & 15) * 8 + (threadIdx.x >> 5);
  int c4 = (threadIdx.x & 31) * 4;
  float4 acc = make_float4(0.f, 0.f, 0.f, 0.f);
  for (int k = 0; k < 128; ++k) {
    float v = V[row * 128 + k];
    float4 l = *(const float4*)(in + k * 128 + c4);
    l.x = lrelu(l.x); l.y = lrelu(l.y); l.z = lrelu(l.z); l.w = lrelu(l.w);
    acc.x = fmaf(v, l.x, acc.x);
    acc.y = fmaf(v, l.y, acc.y);
    acc.z = fmaf(v, l.z, acc.z);
    acc.w = fmaf(v, l.w, acc.w);
  }
  float4 r = *(const float4*)(in + row * 128 + c4);
  float4 o;
  o.x = lrelu(acc.x) + lrelu(r.x);
  o.y = lrelu(acc.y) + lrelu(r.y);
  o.z = lrelu(acc.z) + lrelu(r.z);
  o.w = lrelu(acc.w) + lrelu(r.w);
  *(float4*)(outp + row * 128 + c4) = o;
}

// pass 2: BT = bf16( (lrelu(V @ L) + L)^T ). merged u/i.
__global__ __launch_bounds__(256)
void vg2_k(const float* __restrict__ V, const float* __restrict__ inU,
           const float* __restrict__ inI, u16* __restrict__ outU,
           u16* __restrict__ outI) {
  const float* in = blockIdx.x < 16 ? inU : inI;
  u16* BT = blockIdx.x < 16 ? outU : outI;
  int row = (blockIdx.x & 15) * 8 + (threadIdx.x >> 5);
  int c4 = (threadIdx.x & 31) * 4;
  float4 acc = make_float4(0.f, 0.f, 0.f, 0.f);
  for (int k = 0; k < 128; ++k) {
    float v = V[row * 128 + k];
    float4 l = *(const float4*)(in + k * 128 + c4);
    acc.x = fmaf(v, l.x, acc.x);
    acc.y = fmaf(v, l.y, acc.y);
    acc.z = fmaf(v, l.z, acc.z);
    acc.w = fmaf(v, l.w, acc.w);
  }
  float4 r = *(const float4*)(in + row * 128 + c4);
  BT[(size_t)(c4 + 0) * 128 + row] = f2bf(lrelu(acc.x) + r.x);
  BT[(size_t)(c4 + 1) * 128 + row] = f2bf(lrelu(acc.y) + r.y);
  BT[(size_t)(c4 + 2) * 128 + row] = f2bf(lrelu(acc.z) + r.z);
  BT[(size_t)(c4 + 3) * 128 + row] = f2bf(lrelu(acc.w) + r.w);
}

extern "C" void kernel_launch(void* const* d_in, const int* in_sizes, int n_in,
                              void* d_out, int out_size, void* d_ws, size_t ws_size,
                              hipStream_t stream) {
  const float* u_emb = (const float*)d_in[0];
  const float* i_emb = (const float*)d_in[1];
  const float* u_hyp = (const float*)d_in[2];
  const float* i_hyp = (const float*)d_in[3];
  const float* Vm    = (const float*)d_in[4];
  const int*   rows  = (const int*)d_in[5];
  const int*   cols  = (const int*)d_in[6];
  const float* vals  = (const float*)d_in[7];
  int E = in_sizes[5];

  float* out = (float*)d_out;
  float* OUT_G = out + (size_t)NT * DD;        // gnn_lats [2,N,D]
  float* OUT_H = out + (size_t)3 * NT * DD;    // hyper_lats [2,N,D]

  char* w = (char*)d_ws;
  float* prev = (float*)w;            w += (size_t)NT * DD * 4;
  u16* uuHb   = (u16*)w;              w += (size_t)NT * DD * 2;
  u16* e0bf   = (u16*)w;              w += (size_t)NT * DD * 2;
  u16* prevb  = (u16*)w;              w += (size_t)NT * DD * 2;
  float* latU = (float*)w;            w += 16384 * 4;
  float* latI = (float*)w;            w += 16384 * 4;   // contiguous with latU
  float* lat2U = (float*)w;           w += 16384 * 4;
  float* lat2I = (float*)w;           w += 16384 * 4;
  u16* uhT    = (u16*)w;              w += 16384 * 2;
  u16* ihT    = (u16*)w;              w += 16384 * 2;
  u16* latTu  = (u16*)w;              w += 16384 * 2;
  u16* latTi  = (u16*)w;              w += 16384 * 2;
  int* row_cnt = (int*)w;             w += (size_t)NT * 4;
  int* cursor  = (int*)w;             w += (size_t)NT * 4;  // contiguous with row_cnt
  int* row_ptr = (int*)w;             w += (size_t)(NT + 1) * 4;
  int* tmp     = (int*)w;             w += (size_t)NT * 4;
  int* part    = (int*)w;             w += 512 * 4;
  int2* sedge  = (int2*)w;            w += (size_t)EDG * 8;

  // ---- sort edges by row (once; reused by both layers) ----
  hipMemsetAsync(row_cnt, 0, sizeof(int) * 2 * NT, stream);   // row_cnt + cursor
  hist_k<<<(E + 255) / 256, 256, 0, stream>>>(rows, row_cnt, E);
  scan1_k<<<NCH, 256, 0, stream>>>(row_cnt, tmp, part);
  scan2_k<<<1, 512, 0, stream>>>(part);
  scan3_k<<<NCH, 256, 0, stream>>>(tmp, part, row_ptr);
  scatter_k<<<(E + 255) / 256, 256, 0, stream>>>(rows, cols, vals, row_ptr,
                                                 cursor, sedge, E);

  // ---- hyper projections (also emits e0bf) ----
  transp_both<<<2, 256, 0, stream>>>(u_hyp, i_hyp, uhT, ihT);
  proj_mfma<<<NBU_M + NBI_M, 256, 0, stream>>>(u_emb, i_emb, uhT, ihT, uuHb, e0bf);

  for (int k = 0; k < 2; ++k) {
    float* G = OUT_G + (size_t)k * NT * DD;
    float* H = OUT_H + (size_t)k * NT * DD;
    const u16* pb = k == 0 ? e0bf : prevb;

    // tem = leaky(spmm(prev))
    spmm_row_k<<<NT / 4, 256, 0, stream>>>(row_ptr, sedge, pb, G);

    // hgnn lat chain (users + items merged)
    hipMemsetAsync(latU, 0, sizeof(float) * 2 * 16384, stream);
    tn_mfma<<<NBU_TN + NBI_TN, 256, 0, stream>>>(uuHb, pb, latU, latI);
    vg1_k<<<32, 256, 0, stream>>>(Vm, latU, latI, lat2U, lat2I);
    vg2_k<<<32, 256, 0, stream>>>(Vm, lat2U, lat2I, latTu, latTi);

    // H = lrelu(A @ lat) with fused epilogue
    if (k == 0)
      hyp_mfma<0><<<NBU_M + NBI_M, 256, 0, stream>>>(
          uuHb, latTu, latTi, G, prev, prevb, u_emb, i_emb, H, out);
    else
      hyp_mfma<1><<<NBU_M + NBI_M, 256, 0, stream>>>(
          uuHb, latTu, latTi, G, prev, prevb, u_emb, i_emb, H, out);
  }
}

// Round 7
// 595.965 us; speedup vs baseline: 1.7115x; 1.0899x over previous
//
#include <hip/hip_runtime.h>

#define NU 50000
#define NI 70000
#define NT 120000
#define DD 128
#define EDG 800000
#define NCH ((NT + 255) / 256)      // 469 scan chunks
#define NBU_TN ((NU + 255) / 256)   // 196
#define NBI_TN ((NI + 255) / 256)   // 274
#define NBU_M ((NU + 63) / 64)      // 782
#define NBI_M ((NI + 63) / 64)      // 1094
#define SLOPE 0.5f

typedef __attribute__((ext_vector_type(8))) short bf16x8;
typedef __attribute__((ext_vector_type(4))) float f32x4;
typedef unsigned short u16;
typedef unsigned int u32;

__device__ __forceinline__ float lrelu(float x) { return x >= 0.f ? x : SLOPE * x; }

__device__ __forceinline__ u16 f2bf(float x) {
  union { float f; u32 u; } t; t.f = x;
  u32 r = (t.u + 0x7fffu + ((t.u >> 16) & 1u)) >> 16;
  return (u16)r;
}
__device__ __forceinline__ float bflo(u32 u) {
  union { u32 u; float f; } t; t.u = u << 16; return t.f;
}
__device__ __forceinline__ float bfhi(u32 u) {
  union { u32 u; float f; } t; t.u = u & 0xffff0000u; return t.f;
}
__device__ __forceinline__ float bf1(u16 u) {
  union { u32 u; float f; } t; t.u = (u32)u << 16; return t.f;
}

// ---------------- edge sort (counting sort by row) ----------------

__global__ __launch_bounds__(256)
void hist_k(const int* __restrict__ rows, int* __restrict__ cnt, int E) {
  int e = blockIdx.x * 256 + threadIdx.x;
  if (e < E) atomicAdd(&cnt[rows[e]], 1);
}

__global__ __launch_bounds__(256)
void scan1_k(const int* __restrict__ cnt, int* __restrict__ tmp, int* __restrict__ part) {
  __shared__ int s[256];
  int gid = blockIdx.x * 256 + threadIdx.x;
  s[threadIdx.x] = (gid < NT) ? cnt[gid] : 0;
  __syncthreads();
#pragma unroll
  for (int off = 1; off < 256; off <<= 1) {
    int add = (threadIdx.x >= off) ? s[threadIdx.x - off] : 0;
    __syncthreads();
    s[threadIdx.x] += add;
    __syncthreads();
  }
  if (gid < NT) tmp[gid] = s[threadIdx.x];
  if (threadIdx.x == 255) part[blockIdx.x] = s[255];
}

__global__ __launch_bounds__(512)
void scan2_k(int* __restrict__ part) {
  __shared__ int s[512];
  s[threadIdx.x] = (threadIdx.x < NCH) ? part[threadIdx.x] : 0;
  __syncthreads();
#pragma unroll
  for (int off = 1; off < 512; off <<= 1) {
    int add = (threadIdx.x >= off) ? s[threadIdx.x - off] : 0;
    __syncthreads();
    s[threadIdx.x] += add;
    __syncthreads();
  }
  if (threadIdx.x < NCH) part[threadIdx.x] = s[threadIdx.x];
}

__global__ __launch_bounds__(256)
void scan3_k(const int* __restrict__ tmp, const int* __restrict__ part,
             int* __restrict__ row_ptr) {
  int gid = blockIdx.x * 256 + threadIdx.x;
  if (gid < NT) {
    int off = blockIdx.x ? part[blockIdx.x - 1] : 0;
    row_ptr[gid + 1] = tmp[gid] + off;
  }
  if (gid == 0) row_ptr[0] = 0;
}

__global__ __launch_bounds__(256)
void scatter_k(const int* __restrict__ rows, const int* __restrict__ cols,
               const float* __restrict__ vals, const int* __restrict__ row_ptr,
               int* __restrict__ cursor, int2* __restrict__ sedge, int E) {
  int e = blockIdx.x * 256 + threadIdx.x;
  if (e >= E) return;
  int r = rows[e];
  int p = row_ptr[r] + atomicAdd(&cursor[r], 1);
  int2 ev; ev.x = cols[e]; ev.y = __float_as_int(vals[e]);
  sedge[p] = ev;
}

// out[r,:] = lrelu(sum_e val * src[col,:]) ; bf16 source.
// 1 wave/row; half-waves process even/odd edges (uint2 = 4 dims per lane),
// cross-half shfl reduce, lanes<32 write float4.
__global__ __launch_bounds__(256)
void spmm_row_k(const int* __restrict__ rp, const int2* __restrict__ se,
                const u16* __restrict__ pb, float* __restrict__ G) {
  int wv = threadIdx.x >> 6, lane = threadIdx.x & 63;
  int r = blockIdx.x * 4 + wv;
  int p0 = rp[r], p1 = rp[r + 1];
  int half = lane >> 5, l5 = lane & 31;
  float a0 = 0.f, a1 = 0.f, a2 = 0.f, a3 = 0.f;
  int p = p0 + half;
  for (; p + 2 < p1; p += 4) {
    int2 e1 = se[p];
    int2 e2 = se[p + 2];
    uint2 u1 = *(const uint2*)(pb + (size_t)e1.x * DD + l5 * 4);
    uint2 u2 = *(const uint2*)(pb + (size_t)e2.x * DD + l5 * 4);
    float v1 = __int_as_float(e1.y), v2 = __int_as_float(e2.y);
    a0 = fmaf(v1, bflo(u1.x), a0); a1 = fmaf(v1, bfhi(u1.x), a1);
    a2 = fmaf(v1, bflo(u1.y), a2); a3 = fmaf(v1, bfhi(u1.y), a3);
    a0 = fmaf(v2, bflo(u2.x), a0); a1 = fmaf(v2, bfhi(u2.x), a1);
    a2 = fmaf(v2, bflo(u2.y), a2); a3 = fmaf(v2, bfhi(u2.y), a3);
  }
  if (p < p1) {
    int2 e1 = se[p];
    uint2 u1 = *(const uint2*)(pb + (size_t)e1.x * DD + l5 * 4);
    float v1 = __int_as_float(e1.y);
    a0 = fmaf(v1, bflo(u1.x), a0); a1 = fmaf(v1, bfhi(u1.x), a1);
    a2 = fmaf(v1, bflo(u1.y), a2); a3 = fmaf(v1, bfhi(u1.y), a3);
  }
  a0 += __shfl_xor(a0, 32, 64);
  a1 += __shfl_xor(a1, 32, 64);
  a2 += __shfl_xor(a2, 32, 64);
  a3 += __shfl_xor(a3, 32, 64);
  if (half == 0) {
    float4 o;
    o.x = lrelu(a0); o.y = lrelu(a1); o.z = lrelu(a2); o.w = lrelu(a3);
    *(float4*)(G + (size_t)r * DD + l5 * 4) = o;
  }
}

// ---------------- dense kernels ----------------

// block 0: uhT = bf16(u_hyp^T); block 1: ihT = bf16(i_hyp^T)
__global__ __launch_bounds__(256)
void transp_both(const float* __restrict__ uh, const float* __restrict__ ih,
                 u16* __restrict__ uhT, u16* __restrict__ ihT) {
  const float* B = blockIdx.x ? ih : uh;
  u16* BT = blockIdx.x ? ihT : uhT;
  for (int i = threadIdx.x; i < 16384; i += 256) {
    int r = i >> 7, c = i & 127;
    BT[c * 128 + r] = f2bf(B[r * 128 + c]);
  }
}

// projections: uuHb = bf16(emb @ hyp) for users+items; also emits e0bf = bf16(embeds0).
__global__ __launch_bounds__(256)
void proj_mfma(const float* __restrict__ Au, const float* __restrict__ Ai,
               const u16* __restrict__ BTu, const u16* __restrict__ BTi,
               u16* __restrict__ uuHb, u16* __restrict__ e0bf) {
  int b = blockIdx.x;
  bool usr = b < NBU_M;
  const float* A = usr ? Au : Ai;
  const u16* BT = usr ? BTu : BTi;
  int n = usr ? NU : NI;
  int lb = usr ? b : b - NBU_M;
  int gbase = usr ? 0 : NU;

  int wv = threadIdx.x >> 6, lane = threadIdx.x & 63;
  int t = lane & 15, g = lane >> 4;
  int rowa = lb * 64 + wv * 16 + t;
  int ra = rowa < n ? rowa : (n - 1);
  const float* ap = A + (size_t)ra * DD;

  bf16x8 af[4];
#pragma unroll
  for (int k0 = 0; k0 < 4; ++k0) {
    float4 x = *(const float4*)(ap + k0 * 32 + g * 8);
    float4 y = *(const float4*)(ap + k0 * 32 + g * 8 + 4);
    bf16x8 v;
    v[0] = (short)f2bf(x.x); v[1] = (short)f2bf(x.y);
    v[2] = (short)f2bf(x.z); v[3] = (short)f2bf(x.w);
    v[4] = (short)f2bf(y.x); v[5] = (short)f2bf(y.y);
    v[6] = (short)f2bf(y.z); v[7] = (short)f2bf(y.w);
    af[k0] = v;
  }

  // free bf16 copy of embeds0 (row already converted in registers)
  if (rowa < n) {
#pragma unroll
    for (int k0 = 0; k0 < 4; ++k0)
      *(bf16x8*)(e0bf + (size_t)(gbase + rowa) * DD + k0 * 32 + g * 8) = af[k0];
  }

  f32x4 acc[8];
#pragma unroll
  for (int cb = 0; cb < 8; ++cb) acc[cb] = (f32x4){0.f, 0.f, 0.f, 0.f};
#pragma unroll
  for (int k0 = 0; k0 < 4; ++k0)
#pragma unroll
    for (int cb = 0; cb < 8; ++cb) {
      bf16x8 bfr = *(const bf16x8*)(BT + (size_t)(cb * 16 + t) * 128 + k0 * 32 + g * 8);
      acc[cb] = __builtin_amdgcn_mfma_f32_16x16x32_bf16(af[k0], bfr, acc[cb], 0, 0, 0);
    }

  int rbase = lb * 64 + wv * 16 + g * 4;
#pragma unroll
  for (int cb = 0; cb < 8; ++cb)
#pragma unroll
    for (int j = 0; j < 4; ++j) {
      int lr = rbase + j;
      if (lr < n) uuHb[(size_t)(gbase + lr) * DD + cb * 16 + t] = f2bf(acc[cb][j]);
    }
}

// hyper GEMM (A = bf16 uuHb) + fused epilogue.
// LAYER 0: H=lrelu(acc), prevb=bf16(G+H). LAYER 1: out=e0bf+prevb+G+H.
template<int LAYER>
__global__ __launch_bounds__(256)
void hyp_mfma(const u16* __restrict__ Ab,
              const u16* __restrict__ BTu, const u16* __restrict__ BTi,
              const float* __restrict__ G, u16* __restrict__ prevb,
              const u16* __restrict__ e0bf,
              float* __restrict__ H, float* __restrict__ out) {
  int b = blockIdx.x;
  bool usr = b < NBU_M;
  const u16* BT = usr ? BTu : BTi;
  int n = usr ? NU : NI;
  int lb = usr ? b : b - NBU_M;
  int gbase = usr ? 0 : NU;

  int wv = threadIdx.x >> 6, lane = threadIdx.x & 63;
  int t = lane & 15, g = lane >> 4;
  int rowa = lb * 64 + wv * 16 + t;
  int ra = rowa < n ? rowa : (n - 1);
  const u16* ap = Ab + (size_t)(gbase + ra) * DD;

  bf16x8 af[4];
#pragma unroll
  for (int k0 = 0; k0 < 4; ++k0)
    af[k0] = *(const bf16x8*)(ap + k0 * 32 + g * 8);

  f32x4 acc[8];
#pragma unroll
  for (int cb = 0; cb < 8; ++cb) acc[cb] = (f32x4){0.f, 0.f, 0.f, 0.f};
#pragma unroll
  for (int k0 = 0; k0 < 4; ++k0)
#pragma unroll
    for (int cb = 0; cb < 8; ++cb) {
      bf16x8 bfr = *(const bf16x8*)(BT + (size_t)(cb * 16 + t) * 128 + k0 * 32 + g * 8);
      acc[cb] = __builtin_amdgcn_mfma_f32_16x16x32_bf16(af[k0], bfr, acc[cb], 0, 0, 0);
    }

  int rbase = lb * 64 + wv * 16 + g * 4;
#pragma unroll
  for (int cb = 0; cb < 8; ++cb)
#pragma unroll
    for (int j = 0; j < 4; ++j) {
      int lr = rbase + j;
      if (lr < n) {
        size_t gi = (size_t)(gbase + lr) * DD + cb * 16 + t;
        float h = lrelu(acc[cb][j]);
        H[gi] = h;
        if (LAYER == 0) {
          prevb[gi] = f2bf(G[gi] + h);
        } else {
          out[gi] = bf1(e0bf[gi]) + bf1(prevb[gi]) + G[gi] + h;
        }
      }
    }
}

// lat reduction via MFMA: lat[h][d] += sum_r A[r][h]*B[r][d] over this block's
// row chunk. 32-row K-slabs staged in LDS transposed+pair-packed, swizzled.
__global__ __launch_bounds__(256)
void tn_mfma(const u16* __restrict__ Ab, const u16* __restrict__ Bb,
             float* __restrict__ latU, float* __restrict__ latI) {
  __shared__ u32 ATs[2048];   // [128 c][16 rp] u32
  __shared__ u32 BTs[2048];
  int b = blockIdx.x;
  bool usr = b < NBU_TN;
  int n = usr ? NU : NI;
  int gbase = usr ? 0 : NU;
  float* outp = usr ? latU : latI;
  int r0c = (usr ? b : b - NBU_TN) * 256;
  int r1c = min(r0c + 256, n);

  int tid = threadIdx.x;
  int rp = tid & 15;           // row-pair index within 32-row slab
  int sg = tid >> 4;           // 0..15 : 8-col segment
  int wv = tid >> 6, lane = tid & 63;
  int t = lane & 15, g = lane >> 4;
  int wr = wv >> 1, wc = wv & 1;   // wave tile: 4 h-tiles x 4 d-tiles

  f32x4 acc[4][4];
#pragma unroll
  for (int a = 0; a < 4; ++a)
#pragma unroll
    for (int c2 = 0; c2 < 4; ++c2) acc[a][c2] = (f32x4){0.f, 0.f, 0.f, 0.f};

  for (int r0 = r0c; r0 < r1c; r0 += 32) {
    int ra = r0 + 2 * rp, rb2 = ra + 1;
    uint4 a0 = {0,0,0,0}, a1 = {0,0,0,0}, b0 = {0,0,0,0}, b1 = {0,0,0,0};
    if (ra < r1c) {
      a0 = *(const uint4*)(Ab + (size_t)(gbase + ra) * DD + sg * 8);
      b0 = *(const uint4*)(Bb + (size_t)(gbase + ra) * DD + sg * 8);
    }
    if (rb2 < r1c) {
      a1 = *(const uint4*)(Ab + (size_t)(gbase + rb2) * DD + sg * 8);
      b1 = *(const uint4*)(Bb + (size_t)(gbase + rb2) * DD + sg * 8);
    }
    __syncthreads();   // previous slab's reads complete
#pragma unroll
    for (int j = 0; j < 8; ++j) {
      u32 alo = ((const u32*)&a0)[j >> 1], ahi = ((const u32*)&a1)[j >> 1];
      u32 blo = ((const u32*)&b0)[j >> 1], bhi = ((const u32*)&b1)[j >> 1];
      u32 wa, wb;
      if (j & 1) {
        wa = (alo >> 16) | (ahi & 0xffff0000u);
        wb = (blo >> 16) | (bhi & 0xffff0000u);
      } else {
        wa = (alo & 0xffffu) | (ahi << 16);
        wb = (blo & 0xffffu) | (bhi << 16);
      }
      int c = sg * 8 + j;
      int idx = c * 16 + (rp ^ ((j & 3) << 2));
      ATs[idx] = wa;
      BTs[idx] = wb;
    }
    __syncthreads();   // slab visible

    bf16x8 afr[4], bfr[4];
#pragma unroll
    for (int a = 0; a < 4; ++a) {
      int c = (wr * 4 + a) * 16 + t;
      afr[a] = *(const bf16x8*)&ATs[c * 16 + ((g ^ (c & 3)) << 2)];
    }
#pragma unroll
    for (int c2 = 0; c2 < 4; ++c2) {
      int c = (wc * 4 + c2) * 16 + t;
      bfr[c2] = *(const bf16x8*)&BTs[c * 16 + ((g ^ (c & 3)) << 2)];
    }
#pragma unroll
    for (int a = 0; a < 4; ++a)
#pragma unroll
      for (int c2 = 0; c2 < 4; ++c2)
        acc[a][c2] = __builtin_amdgcn_mfma_f32_16x16x32_bf16(
            afr[a], bfr[c2], acc[a][c2], 0, 0, 0);
  }

#pragma unroll
  for (int a = 0; a < 4; ++a) {
    int h = (wr * 4 + a) * 16 + g * 4;
#pragma unroll
    for (int c2 = 0; c2 < 4; ++c2) {
      int d = (wc * 4 + c2) * 16 + t;
#pragma unroll
      for (int j = 0; j < 4; ++j)
        atomicAdd(outp + (h + j) * 128 + d, acc[a][c2][j]);
    }
  }
}

// pass 1: out = lrelu(V @ L) + L, where L = lrelu(in_raw). merged u/i, 32 blocks.
__global__ __launch_bounds__(256)
void vg1_k(const float* __restrict__ V, const float* __restrict__ inU,
           const float* __restrict__ inI, float* __restrict__ outU,
           float* __restrict__ outI) {
  const float* in = blockIdx.x < 16 ? inU : inI;
  float* outp = blockIdx.x < 16 ? outU : outI;
  int row = (blockIdx.x & 15) * 8 + (threadIdx.x >> 5);
  int c4 = (threadIdx.x & 31) * 4;
  float4 acc = make_float4(0.f, 0.f, 0.f, 0.f);
  for (int k = 0; k < 128; ++k) {
    float v = V[row * 128 + k];
    float4 l = *(const float4*)(in + k * 128 + c4);
    l.x = lrelu(l.x); l.y = lrelu(l.y); l.z = lrelu(l.z); l.w = lrelu(l.w);
    acc.x = fmaf(v, l.x, acc.x);
    acc.y = fmaf(v, l.y, acc.y);
    acc.z = fmaf(v, l.z, acc.z);
    acc.w = fmaf(v, l.w, acc.w);
  }
  float4 r = *(const float4*)(in + row * 128 + c4);
  float4 o;
  o.x = lrelu(acc.x) + lrelu(r.x);
  o.y = lrelu(acc.y) + lrelu(r.y);
  o.z = lrelu(acc.z) + lrelu(r.z);
  o.w = lrelu(acc.w) + lrelu(r.w);
  *(float4*)(outp + row * 128 + c4) = o;
}

// pass 2: BT = bf16( (lrelu(V @ L) + L)^T ). merged u/i.
__global__ __launch_bounds__(256)
void vg2_k(const float* __restrict__ V, const float* __restrict__ inU,
           const float* __restrict__ inI, u16* __restrict__ outU,
           u16* __restrict__ outI) {
  const float* in = blockIdx.x < 16 ? inU : inI;
  u16* BT = blockIdx.x < 16 ? outU : outI;
  int row = (blockIdx.x & 15) * 8 + (threadIdx.x >> 5);
  int c4 = (threadIdx.x & 31) * 4;
  float4 acc = make_float4(0.f, 0.f, 0.f, 0.f);
  for (int k = 0; k < 128; ++k) {
    float v = V[row * 128 + k];
    float4 l = *(const float4*)(in + k * 128 + c4);
    acc.x = fmaf(v, l.x, acc.x);
    acc.y = fmaf(v, l.y, acc.y);
    acc.z = fmaf(v, l.z, acc.z);
    acc.w = fmaf(v, l.w, acc.w);
  }
  float4 r = *(const float4*)(in + row * 128 + c4);
  BT[(size_t)(c4 + 0) * 128 + row] = f2bf(lrelu(acc.x) + r.x);
  BT[(size_t)(c4 + 1) * 128 + row] = f2bf(lrelu(acc.y) + r.y);
  BT[(size_t)(c4 + 2) * 128 + row] = f2bf(lrelu(acc.z) + r.z);
  BT[(size_t)(c4 + 3) * 128 + row] = f2bf(lrelu(acc.w) + r.w);
}

extern "C" void kernel_launch(void* const* d_in, const int* in_sizes, int n_in,
                              void* d_out, int out_size, void* d_ws, size_t ws_size,
                              hipStream_t stream) {
  const float* u_emb = (const float*)d_in[0];
  const float* i_emb = (const float*)d_in[1];
  const float* u_hyp = (const float*)d_in[2];
  const float* i_hyp = (const float*)d_in[3];
  const float* Vm    = (const float*)d_in[4];
  const int*   rows  = (const int*)d_in[5];
  const int*   cols  = (const int*)d_in[6];
  const float* vals  = (const float*)d_in[7];
  int E = in_sizes[5];

  float* out = (float*)d_out;
  float* OUT_G = out + (size_t)NT * DD;        // gnn_lats [2,N,D]
  float* OUT_H = out + (size_t)3 * NT * DD;    // hyper_lats [2,N,D]

  char* w = (char*)d_ws;
  u16* uuHb   = (u16*)w;              w += (size_t)NT * DD * 2;
  u16* e0bf   = (u16*)w;              w += (size_t)NT * DD * 2;
  u16* prevb  = (u16*)w;              w += (size_t)NT * DD * 2;
  float* latU = (float*)w;            w += 16384 * 4;
  float* latI = (float*)w;            w += 16384 * 4;   // contiguous with latU
  float* lat2U = (float*)w;           w += 16384 * 4;
  float* lat2I = (float*)w;           w += 16384 * 4;
  u16* uhT    = (u16*)w;              w += 16384 * 2;
  u16* ihT    = (u16*)w;              w += 16384 * 2;
  u16* latTu  = (u16*)w;              w += 16384 * 2;
  u16* latTi  = (u16*)w;              w += 16384 * 2;
  int* row_cnt = (int*)w;             w += (size_t)NT * 4;
  int* cursor  = (int*)w;             w += (size_t)NT * 4;  // contiguous with row_cnt
  int* row_ptr = (int*)w;             w += (size_t)(NT + 1) * 4;
  int* tmp     = (int*)w;             w += (size_t)NT * 4;
  int* part    = (int*)w;             w += 512 * 4;
  int2* sedge  = (int2*)w;            w += (size_t)EDG * 8;

  // ---- sort edges by row (once; reused by both layers) ----
  hipMemsetAsync(row_cnt, 0, sizeof(int) * 2 * NT, stream);   // row_cnt + cursor
  hist_k<<<(E + 255) / 256, 256, 0, stream>>>(rows, row_cnt, E);
  scan1_k<<<NCH, 256, 0, stream>>>(row_cnt, tmp, part);
  scan2_k<<<1, 512, 0, stream>>>(part);
  scan3_k<<<NCH, 256, 0, stream>>>(tmp, part, row_ptr);
  scatter_k<<<(E + 255) / 256, 256, 0, stream>>>(rows, cols, vals, row_ptr,
                                                 cursor, sedge, E);

  // ---- hyper projections (also emits e0bf) ----
  transp_both<<<2, 256, 0, stream>>>(u_hyp, i_hyp, uhT, ihT);
  proj_mfma<<<NBU_M + NBI_M, 256, 0, stream>>>(u_emb, i_emb, uhT, ihT, uuHb, e0bf);

  for (int k = 0; k < 2; ++k) {
    float* G = OUT_G + (size_t)k * NT * DD;
    float* H = OUT_H + (size_t)k * NT * DD;
    const u16* pb = k == 0 ? e0bf : prevb;

    // tem = leaky(spmm(prev))
    spmm_row_k<<<NT / 4, 256, 0, stream>>>(row_ptr, sedge, pb, G);

    // hgnn lat chain (users + items merged)
    hipMemsetAsync(latU, 0, sizeof(float) * 2 * 16384, stream);
    tn_mfma<<<NBU_TN + NBI_TN, 256, 0, stream>>>(uuHb, pb, latU, latI);
    vg1_k<<<32, 256, 0, stream>>>(Vm, latU, latI, lat2U, lat2I);
    vg2_k<<<32, 256, 0, stream>>>(Vm, lat2U, lat2I, latTu, latTi);

    // H = lrelu(A @ lat) with fused epilogue
    if (k == 0)
      hyp_mfma<0><<<NBU_M + NBI_M, 256, 0, stream>>>(
          uuHb, latTu, latTi, G, prevb, e0bf, H, out);
    else
      hyp_mfma<1><<<NBU_M + NBI_M, 256, 0, stream>>>(
          uuHb, latTu, latTi, G, prevb, e0bf, H, out);
  }
}